// Round 10
// baseline (3882.726 us; speedup 1.0000x reference)
//
#include <hip/hip_runtime.h>

#define TT 4096
#define BB 128
#define NCH 4
#define L2E 1.4426950408889634f

typedef unsigned uv2 __attribute__((ext_vector_type(2)));
typedef float v2f __attribute__((ext_vector_type(2)));

__device__ __forceinline__ float fexp2(float a) { return __builtin_amdgcn_exp2f(a); }

__device__ __forceinline__ float bpermf(int idx_bytes, float v) {
  return __int_as_float(__builtin_amdgcn_ds_bpermute(idx_bytes, __float_as_int(v)));
}

// Sum of p with partner half (lane ^ 32), replicated in both halves. Pure VALU.
__device__ __forceinline__ float xhalf_sum(float p) {
#if __has_builtin(__builtin_amdgcn_permlane32_swap)
  uv2 r = __builtin_amdgcn_permlane32_swap(__float_as_uint(p), __float_as_uint(p),
                                           false, false);
  return __uint_as_float(r[0]) + __uint_as_float(r[1]);
#else
  return p + bpermf((threadIdx.x ^ 32) << 2, p);
#endif
}

// gx[b,t,g]: g<64 -> 0.5*(x.w_ih[g] + b_ih[g] + b_hh[g])  (r,z; halved for cross-half sum)
//            g>=64 -> x.w_ih[g] + b_ih[g]                 (n x-side, full, per-lane)
// Skips t >= len (gru's prefetch clamps to len-1; fc_apply fills those outputs).
__global__ __launch_bounds__(256) void gx_pre(
    const float* __restrict__ x, const float* __restrict__ w_ih,
    const float* __restrict__ b_ih, const float* __restrict__ b_hh,
    const int* __restrict__ lengths, float* __restrict__ gx) {
  const size_t idx = (size_t)blockIdx.x * 256 + threadIdx.x;  // (b*T+t)*96+g
  const int g = (int)(idx % 96);
  const size_t bt = idx / 96;
  const int b = (int)(bt >> 12);
  const int t = (int)(bt & (TT - 1));
  if (t >= lengths[b]) return;
  const float* xp = x + bt * 6;
  float acc = (g < 64) ? (b_ih[g] + b_hh[g]) : b_ih[g];
#pragma unroll
  for (int i = 0; i < 6; ++i) acc = fmaf(w_ih[g * 6 + i], xp[i], acc);
  gx[idx] = (g < 64) ? 0.5f * acc : acc;
}

struct Chain {
  float h;
  float sAr, sAz, sAn, sBr, sBz, sBn;  // 2-deep gx prefetch slots
  const float* gxb;
  float* hrow;
  int len;
};

// 4 independent GRU chains per wave (batches 4q..4q+3). Lane l: j=l&31 owns
// gate rows j/32+j/64+j; half=l>>5 picks the 16-wide K-slice. Invariant: each
// chain's h register holds h[l&31] (replicated across halves). Phase order per
// step: all 4 chains' bpermutes (latencies overlap) -> slot capture+refill ->
// 4 gate blocks (chain k+1's FMA issue hides chain k's exp2/rcp latency).
__global__ __launch_bounds__(64) __attribute__((amdgpu_waves_per_eu(1, 1)))
void gru_seq4(const int* __restrict__ lengths, const float* __restrict__ w_hh,
              const float* __restrict__ b_hh, const float* __restrict__ gx,
              float* __restrict__ hbuf) {
  __shared__ alignas(16) float hring[NCH][2][32][32];  // per-chain 2-buf ring, 32 KB

  const int q = blockIdx.x;  // quad index
  const int l = threadIdx.x;
  const int j = l & 31;
  const int half = l >> 5;
  const int ko = half << 4;
  const int bko = half << 6;  // bpermute byte-index base

  // shared recurrent weights as float2 pairs (v_pk_fma_f32 operands)
  v2f wr2[8], wz2[8], wn2[8];
  {
    const v2f* pr = (const v2f*)(w_hh + j * 32 + ko);
    const v2f* pz = (const v2f*)(w_hh + (32 + j) * 32 + ko);
    const v2f* pn = (const v2f*)(w_hh + (64 + j) * 32 + ko);
#pragma unroll
    for (int k = 0; k < 8; ++k) wr2[k] = pr[k];
#pragma unroll
    for (int k = 0; k < 8; ++k) wz2[k] = pz[k];
#pragma unroll
    for (int k = 0; k < 8; ++k) wn2[k] = pn[k];
  }
  const float bhn = 0.5f * b_hh[64 + j];  // halved: cross-half sum doubles it

  Chain C0, C1, C2, C3;
  {
    const int b0 = q * NCH;
    C0.len = lengths[b0];     C1.len = lengths[b0 + 1];
    C2.len = lengths[b0 + 2]; C3.len = lengths[b0 + 3];
    C0.gxb = gx + (size_t)b0 * TT * 96;       C1.gxb = C0.gxb + (size_t)TT * 96;
    C2.gxb = C1.gxb + (size_t)TT * 96;        C3.gxb = C2.gxb + (size_t)TT * 96;
    C0.hrow = hbuf + (size_t)b0 * TT * 32;    C1.hrow = C0.hrow + (size_t)TT * 32;
    C2.hrow = C1.hrow + (size_t)TT * 32;      C3.hrow = C2.hrow + (size_t)TT * 32;
    C0.h = C1.h = C2.h = C3.h = 0.0f;
  }

  auto refill = [&](Chain& C, int tp0, float& SR, float& SZ, float& SN) {
    const int tp = (tp0 < C.len) ? tp0 : (C.len - 1);
    const float* gp = C.gxb + (size_t)tp * 96;
    SR = gp[j]; SZ = gp[32 + j]; SN = gp[64 + j];
  };

  auto bperm8 = [&](float h, v2f* hv) {
#pragma unroll
    for (int k = 0; k < 8; ++k) {
      hv[k][0] = bpermf(bko + (k << 3), h);
      hv[k][1] = bpermf(bko + (k << 3) + 4, h);
    }
  };

  auto gates = [&](Chain& C, const v2f* hv, float xr_, float xz_, float xn_) {
    v2f ar = {xr_, 0.f}, az = {xz_, 0.f}, an = {bhn, 0.f};
#pragma unroll
    for (int k = 0; k < 8; ++k) {
      ar = __builtin_elementwise_fma(wr2[k], hv[k], ar);
      az = __builtin_elementwise_fma(wz2[k], hv[k], az);
      an = __builtin_elementwise_fma(wn2[k], hv[k], an);
    }
    const float sr = xhalf_sum(ar[0] + ar[1]);
    const float r = __builtin_amdgcn_rcpf(1.0f + fexp2(-L2E * sr));
    const float sz = xhalf_sum(az[0] + az[1]);
    const float z = __builtin_amdgcn_rcpf(1.0f + fexp2(-L2E * sz));
    const float hn = xhalf_sum(an[0] + an[1]);
    const float ap = fmaf(r, hn, xn_);
    const float qq = __builtin_amdgcn_rcpf(1.0f + fexp2(-2.0f * L2E * ap));
    const float nn = fmaf(2.0f, qq, -1.0f);
    C.h = fmaf(z, C.h - nn, nn);
  };

  // flush chain ring buffer for 32-aligned base: steps [base, base+cnt)
  auto flushc = [&](int cidx, const Chain& C, int base, int cnt) {
    const float4* s4 = (const float4*)(&hring[cidx][(base >> 5) & 1][0][0]);
    float4* dst = (float4*)(C.hrow + (size_t)base * 32);
    const int n4 = cnt * 8;
    for (int qq2 = l; qq2 < n4; qq2 += 64) dst[qq2] = s4[qq2];
  };

#define SUBSTEP(tt, SA)                                                        \
  {                                                                            \
    v2f hv0[8], hv1[8], hv2[8], hv3[8];                                        \
    bperm8(C0.h, hv0); bperm8(C1.h, hv1);                                      \
    bperm8(C2.h, hv2); bperm8(C3.h, hv3);                                      \
    const float x0r = C0.s##SA##r, x0z = C0.s##SA##z, x0n = C0.s##SA##n;       \
    const float x1r = C1.s##SA##r, x1z = C1.s##SA##z, x1n = C1.s##SA##n;       \
    const float x2r = C2.s##SA##r, x2z = C2.s##SA##z, x2n = C2.s##SA##n;       \
    const float x3r = C3.s##SA##r, x3z = C3.s##SA##z, x3n = C3.s##SA##n;       \
    refill(C0, (tt) + 2, C0.s##SA##r, C0.s##SA##z, C0.s##SA##n);               \
    refill(C1, (tt) + 2, C1.s##SA##r, C1.s##SA##z, C1.s##SA##n);               \
    refill(C2, (tt) + 2, C2.s##SA##r, C2.s##SA##z, C2.s##SA##n);               \
    refill(C3, (tt) + 2, C3.s##SA##r, C3.s##SA##z, C3.s##SA##n);               \
    gates(C0, hv0, x0r, x0z, x0n);                                             \
    gates(C1, hv1, x1r, x1z, x1n);                                             \
    gates(C2, hv2, x2r, x2z, x2n);                                             \
    gates(C3, hv3, x3r, x3z, x3n);                                             \
    hring[0][((tt) >> 5) & 1][(tt) & 31][j] = C0.h;                            \
    hring[1][((tt) >> 5) & 1][(tt) & 31][j] = C1.h;                            \
    hring[2][((tt) >> 5) & 1][(tt) & 31][j] = C2.h;                            \
    hring[3][((tt) >> 5) & 1][(tt) & 31][j] = C3.h;                            \
    if (((tt) & 31) == 31) {                                                   \
      flushc(0, C0, (tt) - 31, 32); flushc(1, C1, (tt) - 31, 32);              \
      flushc(2, C2, (tt) - 31, 32); flushc(3, C3, (tt) - 31, 32);              \
    }                                                                          \
  }

  // prologue: fill both slots per chain
  refill(C0, 0, C0.sAr, C0.sAz, C0.sAn); refill(C0, 1, C0.sBr, C0.sBz, C0.sBn);
  refill(C1, 0, C1.sAr, C1.sAz, C1.sAn); refill(C1, 1, C1.sBr, C1.sBz, C1.sBn);
  refill(C2, 0, C2.sAr, C2.sAz, C2.sAn); refill(C2, 1, C2.sBr, C2.sBz, C2.sBn);
  refill(C3, 0, C3.sAr, C3.sAz, C3.sAn); refill(C3, 1, C3.sBr, C3.sBz, C3.sBn);

  int tmin = C0.len;
  tmin = (C1.len < tmin) ? C1.len : tmin;
  tmin = (C2.len < tmin) ? C2.len : tmin;
  tmin = (C3.len < tmin) ? C3.len : tmin;

  int t = 0;
  while (t + 2 <= tmin) {
    SUBSTEP(t, A);
    SUBSTEP(t + 1, B);
    t += 2;
  }
  if (t < tmin) {
    SUBSTEP(t, A);
    ++t;
  }

  // per-chain tails (lengths sorted descending -> short)
  auto tail_run = [&](int cidx, Chain& C, int t0) {
    int tc = t0;
    if (tc < C.len) {
      refill(C, tc, C.sAr, C.sAz, C.sAn);
      refill(C, tc + 1, C.sBr, C.sBz, C.sBn);
      auto tstep = [&](float& SR, float& SZ, float& SN) {
        v2f hv[8];
        bperm8(C.h, hv);
        const float xr_ = SR, xz_ = SZ, xn_ = SN;
        refill(C, tc + 2, SR, SZ, SN);
        gates(C, hv, xr_, xz_, xn_);
        hring[cidx][(tc >> 5) & 1][tc & 31][j] = C.h;
        if ((tc & 31) == 31) flushc(cidx, C, tc - 31, 32);
        ++tc;
      };
      while (tc + 2 <= C.len) {
        tstep(C.sAr, C.sAz, C.sAn);
        tstep(C.sBr, C.sBz, C.sBn);
      }
      if (tc < C.len) tstep(C.sAr, C.sAz, C.sAn);
    }
    const int rem = C.len & 31;
    if (rem) flushc(cidx, C, C.len - rem, rem);
  };
  tail_run(0, C0, t);
  tail_run(1, C1, t);
  tail_run(2, C2, t);
  tail_run(3, C3, t);
#undef SUBSTEP
}

// out[b,t,:] = (t < len[b]) ? h[b,t,:] @ fc_w^T + fc_b : fc_b
__global__ __launch_bounds__(256) void fc_apply(
    const float* __restrict__ hbuf, const int* __restrict__ lengths,
    const float* __restrict__ fc_w, const float* __restrict__ fc_b,
    float* __restrict__ out) {
  const int idx = blockIdx.x * 256 + threadIdx.x;  // flattened (b,t)
  const int b = idx >> 12;
  const int t = idx & (TT - 1);
  const float fb0 = fc_b[0], fb1 = fc_b[1];
  float* op = out + (size_t)idx * 2;
  if (t >= lengths[b]) {
    op[0] = fb0;
    op[1] = fb1;
    return;
  }
  const float4* hp = (const float4*)(hbuf + (size_t)idx * 32);
  const float4* w0 = (const float4*)(fc_w);
  const float4* w1 = (const float4*)(fc_w + 32);
  float o0 = 0.f, o1 = 0.f;
#pragma unroll
  for (int qq = 0; qq < 8; ++qq) {
    const float4 hv = hp[qq], a = w0[qq], c = w1[qq];
    o0 += hv.x * a.x + hv.y * a.y + hv.z * a.z + hv.w * a.w;
    o1 += hv.x * c.x + hv.y * c.y + hv.z * c.z + hv.w * c.w;
  }
  op[0] = o0 + fb0;
  op[1] = o1 + fb1;
}

// Fallback (ws too small): self-contained single kernel.
__global__ __launch_bounds__(64) void gru_fallback(
    const float* __restrict__ x, const int* __restrict__ lengths,
    const float* __restrict__ w_ih, const float* __restrict__ w_hh,
    const float* __restrict__ b_ih, const float* __restrict__ b_hh,
    const float* __restrict__ fc_w, const float* __restrict__ fc_b,
    float* __restrict__ out) {
  const int b = blockIdx.x;
  const int l = threadIdx.x;
  const int j = l & 31;
  const int half = l >> 5;
  const int ko = half << 4;
  const int len = lengths[b];

  float wr[16], wz[16], wn[16];
#pragma unroll
  for (int k = 0; k < 16; ++k) wr[k] = w_hh[j * 32 + ko + k] * L2E;
#pragma unroll
  for (int k = 0; k < 16; ++k) wz[k] = w_hh[(32 + j) * 32 + ko + k] * L2E;
#pragma unroll
  for (int k = 0; k < 16; ++k) wn[k] = w_hh[(64 + j) * 32 + ko + k] * (2.0f * L2E);
  float wxr[6], wxz[6], wxn[6];
#pragma unroll
  for (int i = 0; i < 6; ++i) wxr[i] = w_ih[j * 6 + i] * (0.5f * L2E);
#pragma unroll
  for (int i = 0; i < 6; ++i) wxz[i] = w_ih[(32 + j) * 6 + i] * (0.5f * L2E);
#pragma unroll
  for (int i = 0; i < 6; ++i) wxn[i] = w_ih[(64 + j) * 6 + i] * (2.0f * L2E);
  const float br = (b_ih[j] + b_hh[j]) * (0.5f * L2E);
  const float bz = (b_ih[32 + j] + b_hh[32 + j]) * (0.5f * L2E);
  const float bxn = b_ih[64 + j] * (2.0f * L2E);
  const float bhn = b_hh[64 + j] * L2E;
  const float fcw = fc_w[half * 32 + j];
  const float fcb = fc_b[half];

  const float* xb = x + (size_t)b * (TT * 6);
  float* ob = out + (size_t)b * (TT * 2);
  const int bko = half << 6;
  float h = 0.0f;

  v2f cx[3], nx[3];
  {
    const v2f* xp = (const v2f*)xb;
    cx[0] = xp[0]; cx[1] = xp[1]; cx[2] = xp[2];
  }
  for (int t = 0; t < len; ++t) {
    const int tn = (t + 1 < len) ? (t + 1) : t;
    const v2f* xp = (const v2f*)(xb + tn * 6);
    nx[0] = xp[0]; nx[1] = xp[1]; nx[2] = xp[2];
    float xr = br, xz = bz, xn = bxn;
#pragma unroll
    for (int i = 0; i < 3; ++i) {
      const float c0 = cx[i][0], c1 = cx[i][1];
      xr = fmaf(wxr[2 * i], c0, xr); xr = fmaf(wxr[2 * i + 1], c1, xr);
      xz = fmaf(wxz[2 * i], c0, xz); xz = fmaf(wxz[2 * i + 1], c1, xz);
      xn = fmaf(wxn[2 * i], c0, xn); xn = fmaf(wxn[2 * i + 1], c1, xn);
    }
    float hbv[16];
#pragma unroll
    for (int k = 0; k < 16; ++k) hbv[k] = bpermf(bko + (k << 2), h);
    float ar0 = xr, ar1 = 0.f, az0 = xz, az1 = 0.f, an0 = bhn, an1 = 0.f;
#pragma unroll
    for (int k = 0; k < 8; ++k) {
      ar0 = fmaf(wr[k], hbv[k], ar0);
      ar1 = fmaf(wr[k + 8], hbv[k + 8], ar1);
      az0 = fmaf(wz[k], hbv[k], az0);
      az1 = fmaf(wz[k + 8], hbv[k + 8], az1);
      an0 = fmaf(wn[k], hbv[k], an0);
      an1 = fmaf(wn[k + 8], hbv[k + 8], an1);
    }
    const float sr = xhalf_sum(ar0 + ar1);
    const float r = __builtin_amdgcn_rcpf(1.0f + fexp2(-sr));
    const float sz = xhalf_sum(az0 + az1);
    const float z = __builtin_amdgcn_rcpf(1.0f + fexp2(-sz));
    const float hn = xhalf_sum(an0 + an1);
    const float ap = fmaf(r, hn, xn);
    const float qq = __builtin_amdgcn_rcpf(1.0f + fexp2(-ap));
    const float nn = fmaf(2.0f, qq, -1.0f);
    h = fmaf(z, h - nn, nn);
    float p = h * fcw;
    p += __shfl_xor(p, 1);
    p += __shfl_xor(p, 2);
    p += __shfl_xor(p, 4);
    p += __shfl_xor(p, 8);
    p += __shfl_xor(p, 16);
    if (j == 0) ob[t * 2 + half] = p + fcb;
#pragma unroll
    for (int i = 0; i < 3; ++i) cx[i] = nx[i];
  }
  const float fb0 = fc_b[0], fb1 = fc_b[1];
  for (int idx = len * 2 + l; idx < TT * 2; idx += 64)
    ob[idx] = (idx & 1) ? fb1 : fb0;
}

extern "C" void kernel_launch(void* const* d_in, const int* in_sizes, int n_in,
                              void* d_out, int out_size, void* d_ws, size_t ws_size,
                              hipStream_t stream) {
  const float* x       = (const float*)d_in[0];
  const int*   lengths = (const int*)d_in[1];
  const float* w_ih    = (const float*)d_in[2];
  const float* w_hh    = (const float*)d_in[3];
  const float* b_ih    = (const float*)d_in[4];
  const float* b_hh    = (const float*)d_in[5];
  const float* fc_w    = (const float*)d_in[6];
  const float* fc_b    = (const float*)d_in[7];
  float* outp = (float*)d_out;

  const size_t hbuf_elems = (size_t)BB * TT * 32;               // 64 MB
  const size_t gx_elems   = (size_t)BB * TT * 96;               // 192 MB
  const size_t need = (hbuf_elems + gx_elems) * sizeof(float);  // 256 MB
  if (ws_size >= need) {
    float* hbuf = (float*)d_ws;
    float* gx = (float*)d_ws + hbuf_elems;
    hipLaunchKernelGGL(gx_pre, dim3((BB * TT * 96) / 256), dim3(256), 0, stream,
                       x, w_ih, b_ih, b_hh, lengths, gx);
    hipLaunchKernelGGL(gru_seq4, dim3(BB / NCH), dim3(64), 0, stream,
                       lengths, w_hh, b_hh, gx, hbuf);
    hipLaunchKernelGGL(fc_apply, dim3((BB * TT) / 256), dim3(256), 0, stream,
                       hbuf, lengths, fc_w, fc_b, outp);
  } else {
    hipLaunchKernelGGL(gru_fallback, dim3(BB), dim3(64), 0, stream,
                       x, lengths, w_ih, w_hh, b_ih, b_hh, fc_w, fc_b, outp);
  }
}

// Round 11
// 2009.092 us; speedup vs baseline: 1.9326x; 1.9326x over previous
//
#include <hip/hip_runtime.h>

#define TT 4096
#define BB 128
#define L2E 1.4426950408889634f

typedef unsigned uv2 __attribute__((ext_vector_type(2)));
typedef float v2f __attribute__((ext_vector_type(2)));

__device__ __forceinline__ float fexp2(float a) { return __builtin_amdgcn_exp2f(a); }

__device__ __forceinline__ float bpermf(int idx_bytes, float v) {
  return __int_as_float(__builtin_amdgcn_ds_bpermute(idx_bytes, __float_as_int(v)));
}

// Sum of p with partner half (lane ^ 32), replicated in both halves. Pure VALU.
__device__ __forceinline__ float xhalf_sum(float p) {
#if __has_builtin(__builtin_amdgcn_permlane32_swap)
  uv2 r = __builtin_amdgcn_permlane32_swap(__float_as_uint(p), __float_as_uint(p),
                                           false, false);
  return __uint_as_float(r[0]) + __uint_as_float(r[1]);
#else
  return p + bpermf((threadIdx.x ^ 32) << 2, p);
#endif
}

// gx[b,t,g]: g<64 -> 0.5*(x.w_ih[g] + b_ih[g] + b_hh[g])  (r,z; halved for cross-half sum)
//            g>=64 -> x.w_ih[g] + b_ih[g]                 (n x-side, full, per-lane)
__global__ __launch_bounds__(256) void gx_pre(
    const float* __restrict__ x, const float* __restrict__ w_ih,
    const float* __restrict__ b_ih, const float* __restrict__ b_hh,
    const int* __restrict__ lengths, float* __restrict__ gx) {
  const size_t idx = (size_t)blockIdx.x * 256 + threadIdx.x;  // (b*T+t)*96+g
  const int g = (int)(idx % 96);
  const size_t bt = idx / 96;
  const int b = (int)(bt >> 12);
  const int t = (int)(bt & (TT - 1));
  if (t >= lengths[b]) return;
  const float* xp = x + bt * 6;
  float acc = (g < 64) ? (b_ih[g] + b_hh[g]) : b_ih[g];
#pragma unroll
  for (int i = 0; i < 6; ++i) acc = fmaf(w_ih[g * 6 + i], xp[i], acc);
  gx[idx] = (g < 64) ? 0.5f * acc : acc;
}

// 2 independent GRU chains per wave (batches 2q, 2q+1). Lane l: j=l&31 owns
// gate rows j/32+j/64+j; half=l>>5 picks the 16-wide K-slice. Each chain's h
// register holds h[l&31] (replicated across halves). hv arrays are declared
// IN the substep scope with static indexing only (no pointer-passing into
// helpers) so mem2reg keeps them in VGPRs — R10's pointer-escape demoted them
// to scratch (VGPR stuck at 132, 4x slowdown).
__global__ __launch_bounds__(64) __attribute__((amdgpu_waves_per_eu(1, 1)))
void gru_seq2(const int* __restrict__ lengths, const float* __restrict__ w_hh,
              const float* __restrict__ b_hh, const float* __restrict__ gx,
              float* __restrict__ hbuf) {
  __shared__ alignas(16) float hring[2][2][32][32];  // chain, buf, step, j = 16 KB

  const int qp = blockIdx.x;  // pair index
  const int l = threadIdx.x;
  const int j = l & 31;
  const int half = l >> 5;
  const int ko = half << 4;
  const int bko = half << 6;  // bpermute byte-index base

  v2f wr2[8], wz2[8], wn2[8];
  {
    const v2f* pr = (const v2f*)(w_hh + j * 32 + ko);
    const v2f* pz = (const v2f*)(w_hh + (32 + j) * 32 + ko);
    const v2f* pn = (const v2f*)(w_hh + (64 + j) * 32 + ko);
#pragma unroll
    for (int k = 0; k < 8; ++k) wr2[k] = pr[k];
#pragma unroll
    for (int k = 0; k < 8; ++k) wz2[k] = pz[k];
#pragma unroll
    for (int k = 0; k < 8; ++k) wn2[k] = pn[k];
  }
  const float bhn = 0.5f * b_hh[64 + j];  // halved: cross-half sum doubles it

  const int bb0 = qp * 2;
  const int len0 = lengths[bb0], len1 = lengths[bb0 + 1];
  const float* gx0 = gx + (size_t)bb0 * TT * 96;
  const float* gx1 = gx0 + (size_t)TT * 96;
  float* hrow0 = hbuf + (size_t)bb0 * TT * 32;
  float* hrow1 = hrow0 + (size_t)TT * 32;

  float h0 = 0.f, h1 = 0.f;
  // 2-deep prefetch slots per chain (named scalars only)
  float a0r, a0z, a0n, b0r, b0z, b0n;  // chain 0: slots A, B
  float a1r, a1z, a1n, b1r, b1z, b1n;  // chain 1: slots A, B

#define REFILL(GXB, LEN, TP0, SR, SZ, SN)                  \
  do {                                                     \
    const int tp_ = ((TP0) < (LEN)) ? (TP0) : ((LEN)-1);   \
    const float* gp_ = (GXB) + (size_t)tp_ * 96;           \
    SR = gp_[j]; SZ = gp_[32 + j]; SN = gp_[64 + j];       \
  } while (0)

// gates: from hv array + captured x-side scalars, update H. hv indexed
// statically via unrolled loop in the SAME scope (no pointer escape).
#define GATES(H, HV, XR, XZ, XN)                                        \
  do {                                                                  \
    v2f ar_ = {(XR), 0.f}, az_ = {(XZ), 0.f}, an_ = {bhn, 0.f};         \
    _Pragma("unroll") for (int k = 0; k < 8; ++k) {                     \
      ar_ = __builtin_elementwise_fma(wr2[k], HV[k], ar_);              \
      az_ = __builtin_elementwise_fma(wz2[k], HV[k], az_);              \
      an_ = __builtin_elementwise_fma(wn2[k], HV[k], an_);              \
    }                                                                   \
    const float sr_ = xhalf_sum(ar_[0] + ar_[1]);                       \
    const float r_ = __builtin_amdgcn_rcpf(1.0f + fexp2(-L2E * sr_));   \
    const float sz_ = xhalf_sum(az_[0] + az_[1]);                       \
    const float z_ = __builtin_amdgcn_rcpf(1.0f + fexp2(-L2E * sz_));   \
    const float hn_ = xhalf_sum(an_[0] + an_[1]);                       \
    const float ap_ = fmaf(r_, hn_, (XN));                              \
    const float qq_ = __builtin_amdgcn_rcpf(1.0f + fexp2(-2.0f * L2E * ap_)); \
    const float nn_ = fmaf(2.0f, qq_, -1.0f);                           \
    H = fmaf(z_, H - nn_, nn_);                                         \
  } while (0)

#define FLUSHC(CIDX, HROW, BASE, CNT)                                   \
  do {                                                                  \
    const float4* s4_ = (const float4*)(&hring[CIDX][((BASE) >> 5) & 1][0][0]); \
    float4* d4_ = (float4*)((HROW) + (size_t)(BASE)*32);                \
    const int n4_ = (CNT)*8;                                            \
    for (int q_ = l; q_ < n4_; q_ += 64) d4_[q_] = s4_[q_];             \
  } while (0)

// one step of both chains; consumes slot S (S0*/S1*), refills it for tt+2
#define SUBSTEP2(tt, S0R, S0Z, S0N, S1R, S1Z, S1N)                      \
  do {                                                                  \
    v2f hv0[8], hv1[8];                                                 \
    _Pragma("unroll") for (int k = 0; k < 8; ++k) {                     \
      hv0[k][0] = bpermf(bko + (k << 3), h0);                           \
      hv0[k][1] = bpermf(bko + (k << 3) + 4, h0);                       \
    }                                                                   \
    _Pragma("unroll") for (int k = 0; k < 8; ++k) {                     \
      hv1[k][0] = bpermf(bko + (k << 3), h1);                           \
      hv1[k][1] = bpermf(bko + (k << 3) + 4, h1);                       \
    }                                                                   \
    const float x0r_ = S0R, x0z_ = S0Z, x0n_ = S0N;                     \
    const float x1r_ = S1R, x1z_ = S1Z, x1n_ = S1N;                     \
    REFILL(gx0, len0, (tt) + 2, S0R, S0Z, S0N);                         \
    REFILL(gx1, len1, (tt) + 2, S1R, S1Z, S1N);                         \
    GATES(h0, hv0, x0r_, x0z_, x0n_);                                   \
    GATES(h1, hv1, x1r_, x1z_, x1n_);                                   \
    hring[0][((tt) >> 5) & 1][(tt)&31][j] = h0;                         \
    hring[1][((tt) >> 5) & 1][(tt)&31][j] = h1;                         \
    if (((tt)&31) == 31) {                                              \
      FLUSHC(0, hrow0, (tt)-31, 32);                                    \
      FLUSHC(1, hrow1, (tt)-31, 32);                                    \
    }                                                                   \
  } while (0)

  REFILL(gx0, len0, 0, a0r, a0z, a0n);
  REFILL(gx0, len0, 1, b0r, b0z, b0n);
  REFILL(gx1, len1, 0, a1r, a1z, a1n);
  REFILL(gx1, len1, 1, b1r, b1z, b1n);

  const int tmin = (len0 < len1) ? len0 : len1;
  int t = 0;
  while (t + 2 <= tmin) {
    SUBSTEP2(t, a0r, a0z, a0n, a1r, a1z, a1n);
    SUBSTEP2(t + 1, b0r, b0z, b0n, b1r, b1z, b1n);
    t += 2;
  }
  if (t < tmin) {
    SUBSTEP2(t, a0r, a0z, a0n, a1r, a1z, a1n);
    ++t;
  }

// single-chain tail step for chain CIDX at time tc, slot S
#define TSTEP(CIDX, H, GXB, LEN, HROW, SR, SZ, SN)                      \
  do {                                                                  \
    v2f hv_[8];                                                         \
    _Pragma("unroll") for (int k = 0; k < 8; ++k) {                     \
      hv_[k][0] = bpermf(bko + (k << 3), H);                            \
      hv_[k][1] = bpermf(bko + (k << 3) + 4, H);                        \
    }                                                                   \
    const float xr_ = SR, xz_ = SZ, xn_ = SN;                           \
    REFILL(GXB, LEN, tc + 2, SR, SZ, SN);                               \
    GATES(H, hv_, xr_, xz_, xn_);                                       \
    hring[CIDX][(tc >> 5) & 1][tc & 31][j] = H;                         \
    if ((tc & 31) == 31) FLUSHC(CIDX, HROW, tc - 31, 32);               \
    ++tc;                                                               \
  } while (0)

  // chain-0 tail
  {
    int tc = t;
    if (tc < len0) {
      REFILL(gx0, len0, tc, a0r, a0z, a0n);
      REFILL(gx0, len0, tc + 1, b0r, b0z, b0n);
      while (tc + 2 <= len0) {
        TSTEP(0, h0, gx0, len0, hrow0, a0r, a0z, a0n);
        TSTEP(0, h0, gx0, len0, hrow0, b0r, b0z, b0n);
      }
      if (tc < len0) TSTEP(0, h0, gx0, len0, hrow0, a0r, a0z, a0n);
    }
    const int rem = len0 & 31;
    if (rem) FLUSHC(0, hrow0, len0 - rem, rem);
  }
  // chain-1 tail
  {
    int tc = t;
    if (tc < len1) {
      REFILL(gx1, len1, tc, a1r, a1z, a1n);
      REFILL(gx1, len1, tc + 1, b1r, b1z, b1n);
      while (tc + 2 <= len1) {
        TSTEP(1, h1, gx1, len1, hrow1, a1r, a1z, a1n);
        TSTEP(1, h1, gx1, len1, hrow1, b1r, b1z, b1n);
      }
      if (tc < len1) TSTEP(1, h1, gx1, len1, hrow1, a1r, a1z, a1n);
    }
    const int rem = len1 & 31;
    if (rem) FLUSHC(1, hrow1, len1 - rem, rem);
  }
#undef SUBSTEP2
#undef TSTEP
#undef GATES
#undef REFILL
#undef FLUSHC
}

// out[b,t,:] = (t < len[b]) ? h[b,t,:] @ fc_w^T + fc_b : fc_b
__global__ __launch_bounds__(256) void fc_apply(
    const float* __restrict__ hbuf, const int* __restrict__ lengths,
    const float* __restrict__ fc_w, const float* __restrict__ fc_b,
    float* __restrict__ out) {
  const int idx = blockIdx.x * 256 + threadIdx.x;  // flattened (b,t)
  const int b = idx >> 12;
  const int t = idx & (TT - 1);
  const float fb0 = fc_b[0], fb1 = fc_b[1];
  float* op = out + (size_t)idx * 2;
  if (t >= lengths[b]) {
    op[0] = fb0;
    op[1] = fb1;
    return;
  }
  const float4* hp = (const float4*)(hbuf + (size_t)idx * 32);
  const float4* w0 = (const float4*)(fc_w);
  const float4* w1 = (const float4*)(fc_w + 32);
  float o0 = 0.f, o1 = 0.f;
#pragma unroll
  for (int qq = 0; qq < 8; ++qq) {
    const float4 hv = hp[qq], a = w0[qq], c = w1[qq];
    o0 += hv.x * a.x + hv.y * a.y + hv.z * a.z + hv.w * a.w;
    o1 += hv.x * c.x + hv.y * c.y + hv.z * c.z + hv.w * c.w;
  }
  op[0] = o0 + fb0;
  op[1] = o1 + fb1;
}

// Fallback (ws too small): self-contained single kernel.
__global__ __launch_bounds__(64) void gru_fallback(
    const float* __restrict__ x, const int* __restrict__ lengths,
    const float* __restrict__ w_ih, const float* __restrict__ w_hh,
    const float* __restrict__ b_ih, const float* __restrict__ b_hh,
    const float* __restrict__ fc_w, const float* __restrict__ fc_b,
    float* __restrict__ out) {
  const int b = blockIdx.x;
  const int l = threadIdx.x;
  const int j = l & 31;
  const int half = l >> 5;
  const int ko = half << 4;
  const int len = lengths[b];

  float wr[16], wz[16], wn[16];
#pragma unroll
  for (int k = 0; k < 16; ++k) wr[k] = w_hh[j * 32 + ko + k] * L2E;
#pragma unroll
  for (int k = 0; k < 16; ++k) wz[k] = w_hh[(32 + j) * 32 + ko + k] * L2E;
#pragma unroll
  for (int k = 0; k < 16; ++k) wn[k] = w_hh[(64 + j) * 32 + ko + k] * (2.0f * L2E);
  float wxr[6], wxz[6], wxn[6];
#pragma unroll
  for (int i = 0; i < 6; ++i) wxr[i] = w_ih[j * 6 + i] * (0.5f * L2E);
#pragma unroll
  for (int i = 0; i < 6; ++i) wxz[i] = w_ih[(32 + j) * 6 + i] * (0.5f * L2E);
#pragma unroll
  for (int i = 0; i < 6; ++i) wxn[i] = w_ih[(64 + j) * 6 + i] * (2.0f * L2E);
  const float br = (b_ih[j] + b_hh[j]) * (0.5f * L2E);
  const float bz = (b_ih[32 + j] + b_hh[32 + j]) * (0.5f * L2E);
  const float bxn = b_ih[64 + j] * (2.0f * L2E);
  const float bhn = b_hh[64 + j] * L2E;
  const float fcw = fc_w[half * 32 + j];
  const float fcb = fc_b[half];

  const float* xb = x + (size_t)b * (TT * 6);
  float* ob = out + (size_t)b * (TT * 2);
  const int bko = half << 6;
  float h = 0.0f;

  v2f cx[3], nx[3];
  {
    const v2f* xp = (const v2f*)xb;
    cx[0] = xp[0]; cx[1] = xp[1]; cx[2] = xp[2];
  }
  for (int t = 0; t < len; ++t) {
    const int tn = (t + 1 < len) ? (t + 1) : t;
    const v2f* xp = (const v2f*)(xb + tn * 6);
    nx[0] = xp[0]; nx[1] = xp[1]; nx[2] = xp[2];
    float xr = br, xz = bz, xn = bxn;
#pragma unroll
    for (int i = 0; i < 3; ++i) {
      const float c0 = cx[i][0], c1 = cx[i][1];
      xr = fmaf(wxr[2 * i], c0, xr); xr = fmaf(wxr[2 * i + 1], c1, xr);
      xz = fmaf(wxz[2 * i], c0, xz); xz = fmaf(wxz[2 * i + 1], c1, xz);
      xn = fmaf(wxn[2 * i], c0, xn); xn = fmaf(wxn[2 * i + 1], c1, xn);
    }
    float hbv[16];
#pragma unroll
    for (int k = 0; k < 16; ++k) hbv[k] = bpermf(bko + (k << 2), h);
    float ar0 = xr, ar1 = 0.f, az0 = xz, az1 = 0.f, an0 = bhn, an1 = 0.f;
#pragma unroll
    for (int k = 0; k < 8; ++k) {
      ar0 = fmaf(wr[k], hbv[k], ar0);
      ar1 = fmaf(wr[k + 8], hbv[k + 8], ar1);
      az0 = fmaf(wz[k], hbv[k], az0);
      az1 = fmaf(wz[k + 8], hbv[k + 8], az1);
      an0 = fmaf(wn[k], hbv[k], an0);
      an1 = fmaf(wn[k + 8], hbv[k + 8], an1);
    }
    const float sr = xhalf_sum(ar0 + ar1);
    const float r = __builtin_amdgcn_rcpf(1.0f + fexp2(-sr));
    const float sz = xhalf_sum(az0 + az1);
    const float z = __builtin_amdgcn_rcpf(1.0f + fexp2(-sz));
    const float hn = xhalf_sum(an0 + an1);
    const float ap = fmaf(r, hn, xn);
    const float qq = __builtin_amdgcn_rcpf(1.0f + fexp2(-ap));
    const float nn = fmaf(2.0f, qq, -1.0f);
    h = fmaf(z, h - nn, nn);
    float p = h * fcw;
    p += __shfl_xor(p, 1);
    p += __shfl_xor(p, 2);
    p += __shfl_xor(p, 4);
    p += __shfl_xor(p, 8);
    p += __shfl_xor(p, 16);
    if (j == 0) ob[t * 2 + half] = p + fcb;
#pragma unroll
    for (int i = 0; i < 3; ++i) cx[i] = nx[i];
  }
  const float fb0 = fc_b[0], fb1 = fc_b[1];
  for (int idx = len * 2 + l; idx < TT * 2; idx += 64)
    ob[idx] = (idx & 1) ? fb1 : fb0;
}

extern "C" void kernel_launch(void* const* d_in, const int* in_sizes, int n_in,
                              void* d_out, int out_size, void* d_ws, size_t ws_size,
                              hipStream_t stream) {
  const float* x       = (const float*)d_in[0];
  const int*   lengths = (const int*)d_in[1];
  const float* w_ih    = (const float*)d_in[2];
  const float* w_hh    = (const float*)d_in[3];
  const float* b_ih    = (const float*)d_in[4];
  const float* b_hh    = (const float*)d_in[5];
  const float* fc_w    = (const float*)d_in[6];
  const float* fc_b    = (const float*)d_in[7];
  float* outp = (float*)d_out;

  const size_t hbuf_elems = (size_t)BB * TT * 32;               // 64 MB
  const size_t gx_elems   = (size_t)BB * TT * 96;               // 192 MB
  const size_t need = (hbuf_elems + gx_elems) * sizeof(float);  // 256 MB
  if (ws_size >= need) {
    float* hbuf = (float*)d_ws;
    float* gx = (float*)d_ws + hbuf_elems;
    hipLaunchKernelGGL(gx_pre, dim3((BB * TT * 96) / 256), dim3(256), 0, stream,
                       x, w_ih, b_ih, b_hh, lengths, gx);
    hipLaunchKernelGGL(gru_seq2, dim3(BB / 2), dim3(64), 0, stream,
                       lengths, w_hh, b_hh, gx, hbuf);
    hipLaunchKernelGGL(fc_apply, dim3((BB * TT) / 256), dim3(256), 0, stream,
                       hbuf, lengths, fc_w, fc_b, outp);
  } else {
    hipLaunchKernelGGL(gru_fallback, dim3(BB), dim3(64), 0, stream,
                       x, lengths, w_ih, w_hh, b_ih, b_hh, fc_w, fc_b, outp);
  }
}

// Round 12
// 1067.140 us; speedup vs baseline: 3.6384x; 1.8827x over previous
//
#include <hip/hip_runtime.h>

#define TT 4096
#define BB 128
#define L2E 1.4426950408889634f

typedef unsigned uv2 __attribute__((ext_vector_type(2)));
typedef float v2f __attribute__((ext_vector_type(2)));

__device__ __forceinline__ float fexp2(float a) { return __builtin_amdgcn_exp2f(a); }

__device__ __forceinline__ float bpermf(int idx_bytes, float v) {
  return __int_as_float(__builtin_amdgcn_ds_bpermute(idx_bytes, __float_as_int(v)));
}

// Sum of p with partner half (lane ^ 32), replicated in both halves. Pure VALU.
// (fallback kernel only)
__device__ __forceinline__ float xhalf_sum(float p) {
#if __has_builtin(__builtin_amdgcn_permlane32_swap)
  uv2 r = __builtin_amdgcn_permlane32_swap(__float_as_uint(p), __float_as_uint(p),
                                           false, false);
  return __uint_as_float(r[0]) + __uint_as_float(r[1]);
#else
  return p + bpermf((threadIdx.x ^ 32) << 2, p);
#endif
}

// h broadcast: two readlanes -> one 64-bit SGPR pair (lo|hi). The 64-bit pack
// is SALU (scalar pipe, parallel to VALU); v_pk_fma_f32 consumes the pair as
// its single allowed SGPR operand. ~10cy to first use vs ~120-150cy ds_bpermute.
__device__ __forceinline__ unsigned long long hpair(float h, int k) {
  unsigned lo = (unsigned)__builtin_amdgcn_readlane(__float_as_int(h), k);
  unsigned hi = (unsigned)__builtin_amdgcn_readlane(__float_as_int(h), k + 1);
  return (unsigned long long)lo | ((unsigned long long)hi << 32);
}

__device__ __forceinline__ void pkfma(v2f& acc, v2f w, unsigned long long hs) {
  asm("v_pk_fma_f32 %0, %1, %2, %0" : "+v"(acc) : "v"(w), "s"(hs));
}

// gx[b,t,g]: g<64  -> L2E*(x.w_ih[g] + b_ih[g] + b_hh[g])    (r,z pre-activation, FULL)
//            g>=64 -> 2*L2E*(x.w_ih[g] + b_ih[g])            (n x-side, FULL)
// Pre-scaled so the serial gate tail needs no multiplies before exp2.
__global__ __launch_bounds__(256) void gx_pre(
    const float* __restrict__ x, const float* __restrict__ w_ih,
    const float* __restrict__ b_ih, const float* __restrict__ b_hh,
    const int* __restrict__ lengths, float* __restrict__ gx) {
  const size_t idx = (size_t)blockIdx.x * 256 + threadIdx.x;  // (b*T+t)*96+g
  const int g = (int)(idx % 96);
  const size_t bt = idx / 96;
  const int b = (int)(bt >> 12);
  const int t = (int)(bt & (TT - 1));
  if (t >= lengths[b]) return;
  const float* xp = x + bt * 6;
  float acc = (g < 64) ? (b_ih[g] + b_hh[g]) : b_ih[g];
#pragma unroll
  for (int i = 0; i < 6; ++i) acc = fmaf(w_ih[g * 6 + i], xp[i], acc);
  gx[idx] = (g < 64) ? (L2E * acc) : (2.0f * L2E * acc);
}

// One wave per batch element. Lane l: j = l&31 owns gate rows j/32+j/64+j with
// FULL K=32 (both halves duplicate; no cross-lane combine anywhere).
// h register holds h[l&31]. Weights (96 VGPRs, pre-scaled) stay resident via
// amdgpu_waves_per_eu(1,1). Broadcast via readlane->SGPR pairs (no LDS window).
// h history -> LDS ring, flushed 32 steps at a time.
__global__ __launch_bounds__(64) __attribute__((amdgpu_waves_per_eu(1, 1)))
void gru_seq(const int* __restrict__ lengths, const float* __restrict__ w_hh,
             const float* __restrict__ b_hh, const float* __restrict__ gx,
             float* __restrict__ hbuf) {
  __shared__ alignas(16) float hring[2][32][32];  // buf, step, j = 8 KB

  const int b = blockIdx.x;
  const int l = threadIdx.x;
  const int j = l & 31;
  const int len = lengths[b];

  // full rows j of the three gates, as v2f pairs, pre-scaled (L2E / 2*L2E)
  v2f wr2[16], wz2[16], wn2[16];
  {
    const v2f* pr = (const v2f*)(w_hh + j * 32);
    const v2f* pz = (const v2f*)(w_hh + (32 + j) * 32);
    const v2f* pn = (const v2f*)(w_hh + (64 + j) * 32);
#pragma unroll
    for (int k = 0; k < 16; ++k) wr2[k] = pr[k] * L2E;
#pragma unroll
    for (int k = 0; k < 16; ++k) wz2[k] = pz[k] * L2E;
#pragma unroll
    for (int k = 0; k < 16; ++k) wn2[k] = pn[k] * (2.0f * L2E);
  }
  const float bhn = 2.0f * L2E * b_hh[64 + j];

  const float* gxb = gx + (size_t)b * TT * 96;
  float* hrow = hbuf + (size_t)b * TT * 32;

  float h = 0.0f;
  int t = 0;

  // 4-deep gx prefetch slots (named scalars; static indexing)
  float g0r, g0z, g0n, g1r, g1z, g1n, g2r, g2z, g2n, g3r, g3z, g3n;
  {
    const int t1 = (1 < len) ? 1 : len - 1, t2 = (2 < len) ? 2 : len - 1,
              t3 = (3 < len) ? 3 : len - 1;
    const float *p0 = gxb, *p1 = gxb + (size_t)t1 * 96,
                *p2 = gxb + (size_t)t2 * 96, *p3 = gxb + (size_t)t3 * 96;
    g0r = p0[j]; g0z = p0[32 + j]; g0n = p0[64 + j];
    g1r = p1[j]; g1z = p1[32 + j]; g1n = p1[64 + j];
    g2r = p2[j]; g2z = p2[32 + j]; g2n = p2[64 + j];
    g3r = p3[j]; g3z = p3[32 + j]; g3n = p3[64 + j];
  }

  auto flush = [&](int base, int cnt) {
    const float4* src = (const float4*)(&hring[(base >> 5) & 1][0][0]);
    float4* dst = (float4*)(hrow + (size_t)base * 32);
    const int n4 = cnt * 8;
    for (int q = l; q < n4; q += 64) dst[q] = src[q];
  };

  auto step = [&](float& GR, float& GZ, float& GN) {
    // broadcast h as 16 SGPR pairs (readlane + SALU pack; no LDS pipe)
    unsigned long long hp[16];
#pragma unroll
    for (int i = 0; i < 16; ++i) hp[i] = hpair(h, 2 * i);

    const float xr_ = GR, xz_ = GZ, xn_ = GN;
    // refill this slot for t+4 (completes within the next 3 iterations)
    {
      const int tp = (t + 4 < len) ? (t + 4) : (len - 1);
      const float* gp = gxb + (size_t)tp * 96;
      GR = gp[j]; GZ = gp[32 + j]; GN = gp[64 + j];
    }

    // 96 MACs as 48 v_pk_fma_f32, six 8-deep chains, full K per lane
    v2f ar0 = {xr_, 0.f}, ar1 = {0.f, 0.f};
    v2f az0 = {xz_, 0.f}, az1 = {0.f, 0.f};
    v2f an0 = {bhn, 0.f}, an1 = {0.f, 0.f};
#pragma unroll
    for (int k = 0; k < 8; ++k) {
      pkfma(ar0, wr2[k], hp[k]);
      pkfma(ar1, wr2[k + 8], hp[k + 8]);
      pkfma(az0, wz2[k], hp[k]);
      pkfma(az1, wz2[k + 8], hp[k + 8]);
      pkfma(an0, wn2[k], hp[k]);
      pkfma(an1, wn2[k + 8], hp[k + 8]);
    }
    const v2f arv = ar0 + ar1, azv = az0 + az1, anv = an0 + an1;
    const float sr = arv[0] + arv[1];  // already *L2E
    const float sz = azv[0] + azv[1];
    const float hn = anv[0] + anv[1];  // already *2L2E (incl bhn)

    const float r = __builtin_amdgcn_rcpf(1.0f + fexp2(-sr));
    const float z = __builtin_amdgcn_rcpf(1.0f + fexp2(-sz));
    const float ap = fmaf(r, hn, xn_);  // *2L2E already
    const float qq = __builtin_amdgcn_rcpf(1.0f + fexp2(-ap));
    const float nn = fmaf(2.0f, qq, -1.0f);
    h = fmaf(z, h - nn, nn);

    hring[(t >> 5) & 1][t & 31][j] = h;  // both halves write identical values
    if ((t & 31) == 31) flush(t - 31, 32);
    ++t;
  };

  while (t + 4 <= len) {
    step(g0r, g0z, g0n);
    step(g1r, g1z, g1n);
    step(g2r, g2z, g2n);
    step(g3r, g3z, g3n);
  }
  if (t < len) step(g0r, g0z, g0n);
  if (t < len) step(g1r, g1z, g1n);
  if (t < len) step(g2r, g2z, g2n);

  const int rem = len & 31;
  if (rem) flush(len - rem, rem);
}

// out[b,t,:] = (t < len[b]) ? h[b,t,:] @ fc_w^T + fc_b : fc_b
__global__ __launch_bounds__(256) void fc_apply(
    const float* __restrict__ hbuf, const int* __restrict__ lengths,
    const float* __restrict__ fc_w, const float* __restrict__ fc_b,
    float* __restrict__ out) {
  const int idx = blockIdx.x * 256 + threadIdx.x;  // flattened (b,t)
  const int b = idx >> 12;
  const int t = idx & (TT - 1);
  const float fb0 = fc_b[0], fb1 = fc_b[1];
  float* op = out + (size_t)idx * 2;
  if (t >= lengths[b]) {
    op[0] = fb0;
    op[1] = fb1;
    return;
  }
  const float4* hp = (const float4*)(hbuf + (size_t)idx * 32);
  const float4* w0 = (const float4*)(fc_w);
  const float4* w1 = (const float4*)(fc_w + 32);
  float o0 = 0.f, o1 = 0.f;
#pragma unroll
  for (int q = 0; q < 8; ++q) {
    const float4 hv = hp[q], a = w0[q], c = w1[q];
    o0 += hv.x * a.x + hv.y * a.y + hv.z * a.z + hv.w * a.w;
    o1 += hv.x * c.x + hv.y * c.y + hv.z * c.z + hv.w * c.w;
  }
  op[0] = o0 + fb0;
  op[1] = o1 + fb1;
}

// Fallback (ws too small): self-contained single kernel (R6 structure).
__global__ __launch_bounds__(64) void gru_fallback(
    const float* __restrict__ x, const int* __restrict__ lengths,
    const float* __restrict__ w_ih, const float* __restrict__ w_hh,
    const float* __restrict__ b_ih, const float* __restrict__ b_hh,
    const float* __restrict__ fc_w, const float* __restrict__ fc_b,
    float* __restrict__ out) {
  const int b = blockIdx.x;
  const int l = threadIdx.x;
  const int j = l & 31;
  const int half = l >> 5;
  const int ko = half << 4;
  const int len = lengths[b];

  float wr[16], wz[16], wn[16];
#pragma unroll
  for (int k = 0; k < 16; ++k) wr[k] = w_hh[j * 32 + ko + k] * L2E;
#pragma unroll
  for (int k = 0; k < 16; ++k) wz[k] = w_hh[(32 + j) * 32 + ko + k] * L2E;
#pragma unroll
  for (int k = 0; k < 16; ++k) wn[k] = w_hh[(64 + j) * 32 + ko + k] * (2.0f * L2E);
  float wxr[6], wxz[6], wxn[6];
#pragma unroll
  for (int i = 0; i < 6; ++i) wxr[i] = w_ih[j * 6 + i] * (0.5f * L2E);
#pragma unroll
  for (int i = 0; i < 6; ++i) wxz[i] = w_ih[(32 + j) * 6 + i] * (0.5f * L2E);
#pragma unroll
  for (int i = 0; i < 6; ++i) wxn[i] = w_ih[(64 + j) * 6 + i] * (2.0f * L2E);
  const float br = (b_ih[j] + b_hh[j]) * (0.5f * L2E);
  const float bz = (b_ih[32 + j] + b_hh[32 + j]) * (0.5f * L2E);
  const float bxn = b_ih[64 + j] * (2.0f * L2E);
  const float bhn = b_hh[64 + j] * L2E;
  const float fcw = fc_w[half * 32 + j];
  const float fcb = fc_b[half];

  const float* xb = x + (size_t)b * (TT * 6);
  float* ob = out + (size_t)b * (TT * 2);
  const int bko = half << 6;
  float h = 0.0f;

  v2f cx[3], nx[3];
  {
    const v2f* xp = (const v2f*)xb;
    cx[0] = xp[0]; cx[1] = xp[1]; cx[2] = xp[2];
  }
  for (int t = 0; t < len; ++t) {
    const int tn = (t + 1 < len) ? (t + 1) : t;
    const v2f* xp = (const v2f*)(xb + tn * 6);
    nx[0] = xp[0]; nx[1] = xp[1]; nx[2] = xp[2];
    float xr = br, xz = bz, xn = bxn;
#pragma unroll
    for (int i = 0; i < 3; ++i) {
      const float c0 = cx[i][0], c1 = cx[i][1];
      xr = fmaf(wxr[2 * i], c0, xr); xr = fmaf(wxr[2 * i + 1], c1, xr);
      xz = fmaf(wxz[2 * i], c0, xz); xz = fmaf(wxz[2 * i + 1], c1, xz);
      xn = fmaf(wxn[2 * i], c0, xn); xn = fmaf(wxn[2 * i + 1], c1, xn);
    }
    float hbv[16];
#pragma unroll
    for (int k = 0; k < 16; ++k) hbv[k] = bpermf(bko + (k << 2), h);
    float ar0 = xr, ar1 = 0.f, az0 = xz, az1 = 0.f, an0 = bhn, an1 = 0.f;
#pragma unroll
    for (int k = 0; k < 8; ++k) {
      ar0 = fmaf(wr[k], hbv[k], ar0);
      ar1 = fmaf(wr[k + 8], hbv[k + 8], ar1);
      az0 = fmaf(wz[k], hbv[k], az0);
      az1 = fmaf(wz[k + 8], hbv[k + 8], az1);
      an0 = fmaf(wn[k], hbv[k], an0);
      an1 = fmaf(wn[k + 8], hbv[k + 8], an1);
    }
    const float sr = xhalf_sum(ar0 + ar1);
    const float r = __builtin_amdgcn_rcpf(1.0f + fexp2(-sr));
    const float sz = xhalf_sum(az0 + az1);
    const float z = __builtin_amdgcn_rcpf(1.0f + fexp2(-sz));
    const float hn = xhalf_sum(an0 + an1);
    const float ap = fmaf(r, hn, xn);
    const float qq = __builtin_amdgcn_rcpf(1.0f + fexp2(-ap));
    const float nn = fmaf(2.0f, qq, -1.0f);
    h = fmaf(z, h - nn, nn);
    float p = h * fcw;
    p += __shfl_xor(p, 1);
    p += __shfl_xor(p, 2);
    p += __shfl_xor(p, 4);
    p += __shfl_xor(p, 8);
    p += __shfl_xor(p, 16);
    if (j == 0) ob[t * 2 + half] = p + fcb;
#pragma unroll
    for (int i = 0; i < 3; ++i) cx[i] = nx[i];
  }
  const float fb0 = fc_b[0], fb1 = fc_b[1];
  for (int idx = len * 2 + l; idx < TT * 2; idx += 64)
    ob[idx] = (idx & 1) ? fb1 : fb0;
}

extern "C" void kernel_launch(void* const* d_in, const int* in_sizes, int n_in,
                              void* d_out, int out_size, void* d_ws, size_t ws_size,
                              hipStream_t stream) {
  const float* x       = (const float*)d_in[0];
  const int*   lengths = (const int*)d_in[1];
  const float* w_ih    = (const float*)d_in[2];
  const float* w_hh    = (const float*)d_in[3];
  const float* b_ih    = (const float*)d_in[4];
  const float* b_hh    = (const float*)d_in[5];
  const float* fc_w    = (const float*)d_in[6];
  const float* fc_b    = (const float*)d_in[7];
  float* outp = (float*)d_out;

  const size_t hbuf_elems = (size_t)BB * TT * 32;               // 64 MB
  const size_t gx_elems   = (size_t)BB * TT * 96;               // 192 MB
  const size_t need = (hbuf_elems + gx_elems) * sizeof(float);  // 256 MB
  if (ws_size >= need) {
    float* hbuf = (float*)d_ws;
    float* gx = (float*)d_ws + hbuf_elems;
    hipLaunchKernelGGL(gx_pre, dim3((BB * TT * 96) / 256), dim3(256), 0, stream,
                       x, w_ih, b_ih, b_hh, lengths, gx);
    hipLaunchKernelGGL(gru_seq, dim3(BB), dim3(64), 0, stream,
                       lengths, w_hh, b_hh, gx, hbuf);
    hipLaunchKernelGGL(fc_apply, dim3((BB * TT) / 256), dim3(256), 0, stream,
                       hbuf, lengths, fc_w, fc_b, outp);
  } else {
    hipLaunchKernelGGL(gru_fallback, dim3(BB), dim3(64), 0, stream,
                       x, lengths, w_ih, w_hh, b_ih, b_hh, fc_w, fc_b, outp);
  }
}